// Round 10
// baseline (133.520 us; speedup 1.0000x reference)
//
#include <hip/hip_runtime.h>
#include <hip/hip_bf16.h>
#include <stdint.h>

// B=8, S=2048, D=256. out[b,d] = (1/S) sum_k w_k v[b,k,d],
// w_k = sum_q P_qk / l_q,  P_qk = exp(s_qk) (0 for masked k), l_q = sum_k P_qk.
//
// Ledger: dur_us ~= sum(ours) + ~87us fixed harness fill. R9 = 130.2 (best):
// fp8 e4m3 QK^T. pass1's byte halving bought only -1.2 -> pass1 is NOT
// byte-bound; compute floor ~3us vs ~18 actual = latency-bound. Root cause:
// grid (8,4,8) = 256 blocks = 1 block/CU = 2 waves/SIMD - no TLP to hide
// vmcnt/barrier stalls. This round (pass1-local):
//  1) ksplit 4->8, normal grid order (R1's ksplit-8 test was confounded by
//     batch->XCD funneling): 512 blocks = 16 waves/CU, 2x latency hiding.
//  2) exp2 fold: log2e folded into Q's fp8 scale (0.25 -> 0.25*log2e);
//     __builtin_amdgcn_exp2f (raw v_exp_f32) replaces __expf's mul+exp.
// All else R9-verbatim.
//
// k_cc:     fp32->bf16 convert + key compaction (slot_of inverse map +
//           kbt pad-chunk zeroing) + lsum/out zeroing.
// k_proj2b: QKV projection GEMM, LDS-tiled, async-DMA staging; z=0 -> qb fp8
//           (x0.25*log2e), z=1 -> kbt fp8 tiles (x0.25), z=2 -> vbc bf16.
// k_pass1v: QK^T fp8 via dbuf global_load_lds staging -> l_q + P tiles (fp8).
// k_wo:     fused: w_k = sum_q P[q][k]/l_q (fp8 P) then out += w . V, w in LDS.

typedef short short8 __attribute__((ext_vector_type(8)));
typedef float floatx4 __attribute__((ext_vector_type(4)));
typedef float floatx2 __attribute__((ext_vector_type(2)));

#define MFMA16(a, b, c) __builtin_amdgcn_mfma_f32_16x16x32_bf16((a), (b), (c), 0, 0, 0)
#define MFMA8(a, b, c) __builtin_amdgcn_mfma_f32_16x16x32_fp8_fp8((a), (b), (c), 0, 0, 0)

// async 16B/lane global->LDS DMA; LDS dst = wave-uniform base + lane*16
#define ASYNC16(gsrc, ldst)                                                    \
    __builtin_amdgcn_global_load_lds(                                          \
        (__attribute__((address_space(1))) void*)(void*)(gsrc),                \
        (__attribute__((address_space(3))) void*)(ldst), 16, 0, 0)

static __device__ __forceinline__ unsigned short f2bf(float f) {
    union { float f; unsigned u; } v; v.f = f;
    unsigned r = v.u + 0x7fffu + ((v.u >> 16) & 1u);
    return (unsigned short)(r >> 16);
}
static __device__ __forceinline__ float bf2f(unsigned short h) {
    union { unsigned u; float f; } v; v.u = ((unsigned)h) << 16;
    return v.f;
}
static __device__ __forceinline__ unsigned char f2fp8(float f) {
    return (unsigned char)__builtin_amdgcn_cvt_pk_fp8_f32(f, f, 0, 0);
}

// ------- k_cc: [0,2144) convert; [2144,2152) compact+pad-zero; rest zero ----
__global__ __launch_bounds__(256) void k_cc(
    const float* __restrict__ nodes, const float* __restrict__ Wq,
    const float* __restrict__ Wk, const float* __restrict__ Wv,
    unsigned short* __restrict__ nbf, unsigned short* __restrict__ wbf,
    const int* __restrict__ mask, int* __restrict__ cnt,
    int* __restrict__ slot_of /* [16384] */,
    unsigned char* __restrict__ kbt,
    float* __restrict__ zbase /* lsum, 16384 f */,
    float* __restrict__ outp /* 2048 f */)
{
    int blk = blockIdx.x;
    if (blk < 2144) {                              // fp32 -> bf16 convert
        int unit = blk * 256 + threadIdx.x;        // one unit = 8 elements
        const float* src;
        unsigned short* dst;
        int off;
        if (unit < 524288) {
            src = nodes; dst = nbf; off = unit * 8;
        } else {
            int j = (unit - 524288) * 8;
            int m = j >> 16;
            int r = j & 65535;
            src = (m == 0) ? Wq : (m == 1 ? Wk : Wv);
            dst = wbf + m * 65536;
            off = r;
        }
        float4 a = *(const float4*)(src + off);
        float4 b = *(const float4*)(src + off + 4);
        short8 o;
        o[0] = f2bf(a.x); o[1] = f2bf(a.y); o[2] = f2bf(a.z); o[3] = f2bf(a.w);
        o[4] = f2bf(b.x); o[5] = f2bf(b.y); o[6] = f2bf(b.z); o[7] = f2bf(b.w);
        *(short8*)(dst + off) = o;
        return;
    }
    if (blk < 2152) {                              // key compaction + inverse map
        if (threadIdx.x < 64) {
            int b = blk - 2144, lane = threadIdx.x;
            int base = 0;
            for (int c = 0; c < 2048; c += 64) {
                int m = mask[b * 2048 + c + lane];
                unsigned long long bal = __ballot(m != 0);
                int pre = __popcll(bal & ((1ull << lane) - 1ull));
                slot_of[b * 2048 + c + lane] = m ? (base + pre) : -1;
                base += __popcll(bal);
            }
            if (lane == 0) cnt[b] = base;
            // zero kbt pad slots of the last chunk (fp8 0 -> exp killed by bias)
            int cntPad = (base + 63) & ~63;
            int pad = cntPad - base;               // [0, 64)
            for (int i = lane; i < pad * 32; i += 64) {
                int slot = base + (i >> 5);
                int du = i & 31;
                size_t off = ((size_t)b * 32 + (slot >> 6)) * 16384
                           + ((size_t)du * 64 + (slot & 63)) * 8;
                *(unsigned long long*)(kbt + off) = 0ull;
            }
        }
        return;
    }
    int idx = (blk - 2152) * 256 + threadIdx.x;    // [0, 4608)
    float4 z = {0.f, 0.f, 0.f, 0.f};
    if (idx < 4096) ((float4*)zbase)[idx] = z;     // lsum: 16384 floats
    else ((float4*)outp)[idx - 4096] = z;          // out: 2048 floats
}

// ------- k_proj2b: 128x128 LDS-tiled GEMM, async staging; K,V -> compacted --
// grid (128, 2, 3); block 256 = 4 waves (2x2), wave computes 64x64.
__global__ __launch_bounds__(256) void k_proj2b(
    const unsigned short* __restrict__ nbf,
    const unsigned short* __restrict__ wbf,
    const float* __restrict__ bq, const float* __restrict__ bk,
    const float* __restrict__ bv,
    const int* __restrict__ slot_of,
    unsigned char* __restrict__ qb, unsigned char* __restrict__ kbt,
    unsigned short* __restrict__ vbc)
{
    __shared__ __align__(16) unsigned short As[128 * 64];
    __shared__ __align__(16) unsigned short Bs[128 * 64];
    int tid = threadIdx.x, lane = tid & 63, wave = tid >> 6;
    int wm = wave & 1, wn = wave >> 1;
    int l15 = lane & 15, quad = lane >> 4;
    int mBase = blockIdx.x * 128;
    int nBase = blockIdx.y * 128;
    int z = blockIdx.z;
    const unsigned short* W = wbf + z * 65536;

    floatx4 acc[4][4] = {};

    for (int kc = 0; kc < 256; kc += 64) {
#pragma unroll
        for (int i = 0; i < 4; ++i) {
            int p = i * 256 + wave * 64 + lane;
            int row = p >> 3;
            int col8 = (p & 7) ^ (row & 7);
            int goff = row * 256 + kc + col8 * 8;
            unsigned short* dstA = &As[(i * 256 + wave * 64) * 8];
            unsigned short* dstB = &Bs[(i * 256 + wave * 64) * 8];
            ASYNC16(nbf + mBase * 256 + goff, dstA);
            ASYNC16(W + nBase * 256 + goff, dstB);
        }
        __syncthreads();
#pragma unroll
        for (int ks = 0; ks < 2; ++ks) {
            int c8 = ks * 4 + quad;
            short8 af[4], bfr[4];
#pragma unroll
            for (int i = 0; i < 4; ++i) {
                int row = wm * 64 + i * 16 + l15;
                af[i] = *(const short8*)(&As[(row * 8 + (c8 ^ (row & 7))) * 8]);
            }
#pragma unroll
            for (int i = 0; i < 4; ++i) {
                int row = wn * 64 + i * 16 + l15;
                bfr[i] = *(const short8*)(&Bs[(row * 8 + (c8 ^ (row & 7))) * 8]);
            }
#pragma unroll
            for (int mi = 0; mi < 4; ++mi)
#pragma unroll
                for (int ni = 0; ni < 4; ++ni)
                    acc[mi][ni] = MFMA16(af[mi], bfr[ni], acc[mi][ni]);
        }
        __syncthreads();
    }

    const float* bias = (z == 0) ? bq : (z == 1 ? bk : bv);
    if (z == 1) {
        // K path: fp8 x0.25, scatter into compacted fragment-tile layout
#pragma unroll
        for (int mi = 0; mi < 4; ++mi)
#pragma unroll
            for (int ni = 0; ni < 4; ++ni) {
                int col = nBase + wn * 64 + ni * 16 + l15;
                float bval = bias[col];
                int du = col >> 3, cj = col & 7;
#pragma unroll
                for (int r = 0; r < 4; ++r) {
                    int row = mBase + wm * 64 + mi * 16 + quad * 4 + r;
                    int slot = slot_of[row];
                    if (slot >= 0) {
                        int b = row >> 11;
                        size_t off = ((size_t)b * 32 + (slot >> 6)) * 16384
                                   + ((size_t)du * 64 + (slot & 63)) * 8 + cj;
                        kbt[off] = f2fp8((acc[mi][ni][r] + bval) * 0.25f);
                    }
                }
            }
    } else if (z == 2) {
        // V path: scatter into slot-compacted [b][slot][d] bf16 layout
#pragma unroll
        for (int mi = 0; mi < 4; ++mi)
#pragma unroll
            for (int ni = 0; ni < 4; ++ni) {
                int col = nBase + wn * 64 + ni * 16 + l15;
                float bval = bias[col];
#pragma unroll
                for (int r = 0; r < 4; ++r) {
                    int row = mBase + wm * 64 + mi * 16 + quad * 4 + r;
                    int slot = slot_of[row];
                    if (slot >= 0) {
                        int b = row >> 11;
                        vbc[((size_t)b * 2048 + slot) * 256 + col] =
                            f2bf(acc[mi][ni][r] + bval);
                    }
                }
            }
    } else {
        // Q path: fp8 x(0.25*log2e) -> with K's 0.25, acc = s*log2e for exp2
        const float scale = 0.25f * 1.44269504088896f;
#pragma unroll
        for (int mi = 0; mi < 4; ++mi)
#pragma unroll
            for (int ni = 0; ni < 4; ++ni) {
                int col = nBase + wn * 64 + ni * 16 + l15;
                float bval = bias[col];
#pragma unroll
                for (int r = 0; r < 4; ++r) {
                    int row = mBase + wm * 64 + mi * 16 + quad * 4 + r;
                    qb[row * 256 + col] = f2fp8((acc[mi][ni][r] + bval) * scale);
                }
            }
    }
}

// ---------------- k_pass1v: QK^T fp8, dbuf async staging, fp8 P -------------
// grid (8 qblk, 8 ksplit, 8 b) = 512 blocks = 2 blocks/CU = 16 waves/CU;
// block 512 = 8 waves; wave owns 32 queries. Chunk = 16KB fp8. Counted
// vmcnt(2) before raw s_barrier keeps next chunk's DMA in flight; vmcnt(0)
// only on the final chunk. P = exp2(acc) via raw v_exp_f32 (log2e folded
// into Q's fp8 scale).
// P tile: [b][ktile(<96)][qcg(64)][lane(64)][8 fp8] (8B coalesced stores).
__global__ __launch_bounds__(512, 2) void k_pass1v(
    const unsigned char* __restrict__ qb, const unsigned char* __restrict__ kbt,
    const int* __restrict__ cnt_g, float* __restrict__ lsum_g,
    unsigned char* __restrict__ pbuf)
{
    __shared__ __align__(16) unsigned char kt[2][16384];   // 2x16KB dbuf
    int tid = threadIdx.x, lane = tid & 63, wave = tid >> 6;
    int l15 = lane & 15, quad = lane >> 4;
    int b = blockIdx.z;
    int cnt = cnt_g[b];
    int nchunk = (cnt + 63) >> 6;
    int qBase = blockIdx.x * 256 + wave * 32;
    int qcg = blockIdx.x * 8 + wave;

    long qf[2][8];
#pragma unroll
    for (int mi = 0; mi < 2; ++mi)
#pragma unroll
        for (int ks = 0; ks < 8; ++ks)
            qf[mi][ks] = *(const long*)(qb + (size_t)(b * 2048 + qBase + mi * 16 + l15) * 256 + ks * 32 + quad * 8);

    // prologue: stage first chunk into buf 0 (8 waves x 2 segs = 16 x 1KB)
    {
        const unsigned char* src = kbt + ((size_t)b * 32 + blockIdx.y) * 16384;
#pragma unroll
        for (int i = 0; i < 2; ++i) {
            int seg = wave * 2 + i;
            ASYNC16(src + seg * 1024 + lane * 16, &kt[0][seg * 1024]);
        }
    }

    float ls[2][4] = {};
    int p = 0;
    for (int c = blockIdx.y; c < nchunk; c += 8, p ^= 1) {
        int cn = c + 8;
        if (cn < nchunk) {                 // prefetch next chunk into other buf
            const unsigned char* srcn = kbt + ((size_t)b * 32 + cn) * 16384;
#pragma unroll
            for (int i = 0; i < 2; ++i) {
                int seg = wave * 2 + i;
                ASYNC16(srcn + seg * 1024 + lane * 16, &kt[p ^ 1][seg * 1024]);
            }
            asm volatile("s_waitcnt vmcnt(2)" ::: "memory");  // cur chunk done
        } else {
            asm volatile("s_waitcnt vmcnt(0)" ::: "memory");
        }
        __builtin_amdgcn_s_barrier();
#pragma unroll
        for (int nt = 0; nt < 4; ++nt) {
            long kf[8];
#pragma unroll
            for (int ks = 0; ks < 8; ++ks)
                kf[ks] = *(const long*)(&kt[p][((ks * 4 + quad) * 64 + nt * 16 + l15) * 8]);
            floatx4 acc[2] = {};
#pragma unroll
            for (int ks = 0; ks < 8; ++ks) {
                acc[0] = MFMA8(qf[0][ks], kf[ks], acc[0]);
                acc[1] = MFMA8(qf[1][ks], kf[ks], acc[1]);
            }
            float bias = (c * 64 + nt * 16 + l15 < cnt) ? 0.0f : -1e30f;
            float e[2][4];
#pragma unroll
            for (int mi = 0; mi < 2; ++mi)
#pragma unroll
                for (int r = 0; r < 4; ++r) {
                    e[mi][r] = __builtin_amdgcn_exp2f(acc[mi][r] + bias);
                    ls[mi][r] += e[mi][r];
                }
            int ktile = c * 4 + nt;
            if (ktile < 96) {
                int w0 = __builtin_amdgcn_cvt_pk_fp8_f32(e[0][0], e[0][1], 0, 0);
                w0 = __builtin_amdgcn_cvt_pk_fp8_f32(e[0][2], e[0][3], w0, 1);
                int w1 = __builtin_amdgcn_cvt_pk_fp8_f32(e[1][0], e[1][1], 0, 0);
                w1 = __builtin_amdgcn_cvt_pk_fp8_f32(e[1][2], e[1][3], w1, 1);
                size_t off = ((((size_t)b * 96 + ktile) * 64 + qcg) * 64 + lane) * 8;
                uint2 pv; pv.x = (unsigned)w0; pv.y = (unsigned)w1;
                *(uint2*)(pbuf + off) = pv;
            }
        }
        __builtin_amdgcn_s_barrier();      // all reads of kt[p] done before
    }                                      // it gets re-staged next+1 iter
#pragma unroll
    for (int mi = 0; mi < 2; ++mi)
#pragma unroll
        for (int r = 0; r < 4; ++r) {
            float v = ls[mi][r];
            v += __shfl_xor(v, 1); v += __shfl_xor(v, 2);
            v += __shfl_xor(v, 4); v += __shfl_xor(v, 8);
            if (l15 == 0)
                atomicAdd(&lsum_g[b * 2048 + qBase + mi * 16 + quad * 4 + r], v);
        }
}

// ---- k_wo: fused w-reduce + out. grid (48 kblk, 8 b); block 256 = 4 waves.
// wave (qh, kt2): reduce 32 qcg for ktile = bx*2+kt2 -> w in LDS; then each
// thread owns one d: out[b,d] += sum over the block's 32 slots of w * vbc.
__global__ __launch_bounds__(256) void k_wo(
    const unsigned char* __restrict__ pbuf, const float* __restrict__ lsum_g,
    const int* __restrict__ cnt_g, const unsigned short* __restrict__ vbc,
    float* __restrict__ outp)
{
    __shared__ float linv_p[2048];   // [qcg(64)][quad(4)][mi*4+r(8)]
    __shared__ float w2_s[2][32];
    int tid = threadIdx.x, lane = tid & 63, wave = tid >> 6;
    int l15 = lane & 15, quad = lane >> 4;
    int b = blockIdx.y;
    int kt2 = wave & 1;
    int qh = wave >> 1;
    int ktile = blockIdx.x * 2 + kt2;              // [0, 96)

#pragma unroll
    for (int i = 0; i < 8; ++i) {
        int idx = i * 256 + tid;
        int qcg = idx >> 5, qd = (idx >> 3) & 3, j = idx & 7;
        int q = qcg * 32 + (j >> 2) * 16 + qd * 4 + (j & 3);
        linv_p[idx] = 1.0f / lsum_g[b * 2048 + q];
    }
    __syncthreads();

    int cnt = cnt_g[b];
    float acc = 0.f;
    if (ktile * 16 < cnt) {
        int qcg0 = qh * 32;
#pragma unroll 4
        for (int qcg = qcg0; qcg < qcg0 + 32; ++qcg) {
            size_t off = ((((size_t)b * 96 + ktile) * 64 + qcg) * 64 + lane) * 8;
            uint2 pv = *(const uint2*)(pbuf + off);
            const float* lv = &linv_p[(qcg * 4 + quad) * 8];
            floatx2 p01 = __builtin_amdgcn_cvt_pk_f32_fp8(pv.x, 0);
            floatx2 p23 = __builtin_amdgcn_cvt_pk_f32_fp8(pv.x, 1);
            floatx2 p45 = __builtin_amdgcn_cvt_pk_f32_fp8(pv.y, 0);
            floatx2 p67 = __builtin_amdgcn_cvt_pk_f32_fp8(pv.y, 1);
            acc += p01[0] * lv[0] + p01[1] * lv[1] + p23[0] * lv[2] + p23[1] * lv[3]
                 + p45[0] * lv[4] + p45[1] * lv[5] + p67[0] * lv[6] + p67[1] * lv[7];
        }
    }
    acc += __shfl_xor(acc, 16);
    acc += __shfl_xor(acc, 32);
    int slot = ktile * 16 + l15;
    if (lane < 16)
        w2_s[qh][kt2 * 16 + l15] = (slot < cnt) ? acc : 0.f;
    __syncthreads();

    // out phase: one thread per d, sum the block's 32 slots
    int d = tid;
    float oacc = 0.f;
#pragma unroll 4
    for (int sl = 0; sl < 32; ++sl) {
        float w = w2_s[0][sl] + w2_s[1][sl];
        if (w != 0.f) {                            // also guards unwritten vbc
            int sg = blockIdx.x * 32 + sl;
            oacc += w * bf2f(vbc[((size_t)b * 2048 + sg) * 256 + d]);
        }
    }
    atomicAdd(&outp[b * 256 + d], oacc * (1.0f / 2048.0f));
}

extern "C" void kernel_launch(void* const* d_in, const int* in_sizes, int n_in,
                              void* d_out, int out_size, void* d_ws, size_t ws_size,
                              hipStream_t stream)
{
    const float* nodes = (const float*)d_in[0];
    const int*   mask  = (const int*)d_in[1];
    const float* Wq    = (const float*)d_in[2];
    const float* bq    = (const float*)d_in[3];
    const float* Wk    = (const float*)d_in[4];
    const float* bk    = (const float*)d_in[5];
    const float* Wv    = (const float*)d_in[6];
    const float* bv    = (const float*)d_in[7];
    float* out = (float*)d_out;

    // workspace layout (same 8MB slot spacing as R7; qb/kbt fp8, use half)
    unsigned char*  qb  = (unsigned char*)d_ws;                 // 4 MB of 8 MB slot
    unsigned short* vbc = (unsigned short*)d_ws + 4194304;      // 8 MB (bf16 V)
    float* lsum = (float*)(vbc + 4194304);                      // 64 KB
    int*   cnt  = (int*)(lsum + 16384);                         // 64 B
    int*   slot_of = cnt + 16;                                  // 64 KB
    unsigned char* kbt = (unsigned char*)(slot_of + 16384);     // 4 MB of 8 MB slot
    unsigned short* X  = (unsigned short*)(kbt + 8388608);
    unsigned short* nbf = X;                                    // 8 MB  (convert/proj)
    unsigned short* wbf = X + 4194304;                          // 0.4 MB (convert/proj)
    unsigned char* pbuf = (unsigned char*)X;                    // 25.2 MB (pass1 onward)

    k_cc<<<2170, 256, 0, stream>>>(nodes, Wq, Wk, Wv, nbf, wbf,
                                   mask, cnt, slot_of, kbt, lsum, out);
    k_proj2b<<<dim3(128, 2, 3), 256, 0, stream>>>(nbf, wbf, bq, bk, bv,
                                                  slot_of, qb, kbt, vbc);
    k_pass1v<<<dim3(8, 8, 8), 512, 0, stream>>>(qb, kbt, cnt, lsum, pbuf);
    k_wo<<<dim3(48, 8), 256, 0, stream>>>(pbuf, lsum, cnt, vbc, out);
}

// Round 11
// 131.134 us; speedup vs baseline: 1.0182x; 1.0182x over previous
//
#include <hip/hip_runtime.h>
#include <hip/hip_bf16.h>
#include <stdint.h>

// B=8, S=2048, D=256. out[b,d] = (1/S) sum_k w_k v[b,k,d],
// w_k = sum_q P_qk / l_q,  P_qk = exp(s_qk) (0 for masked k), l_q = sum_k P_qk.
//
// Ledger: dur_us ~= sum(ours) + ~87us fixed harness fill. R9 = 130.2 (best).
// R10 (ksplit 8 + exp2) REGRESSED +3.3 -> ksplit reverted to 4 (2nd
// confirmation that deeper ksplit hurts: shorter dbuf pipeline + 2x qb/lsum).
// This round (one isolated variable on R9): keep the exp2 fold only -
// log2e folded into Q's fp8 scale, __builtin_amdgcn_exp2f replaces __expf
// (deletes one v_mul per exp, 32/thread/chunk). All else R9-verbatim.
//
// k_cc:     fp32->bf16 convert + key compaction (slot_of inverse map +
//           kbt pad-chunk zeroing) + lsum/out zeroing.
// k_proj2b: QKV projection GEMM, LDS-tiled, async-DMA staging; z=0 -> qb fp8
//           (x0.25*log2e), z=1 -> kbt fp8 tiles (x0.25), z=2 -> vbc bf16.
// k_pass1v: QK^T fp8 via dbuf global_load_lds staging -> l_q + P tiles (fp8).
// k_wo:     fused: w_k = sum_q P[q][k]/l_q (fp8 P) then out += w . V, w in LDS.

typedef short short8 __attribute__((ext_vector_type(8)));
typedef float floatx4 __attribute__((ext_vector_type(4)));
typedef float floatx2 __attribute__((ext_vector_type(2)));

#define MFMA16(a, b, c) __builtin_amdgcn_mfma_f32_16x16x32_bf16((a), (b), (c), 0, 0, 0)
#define MFMA8(a, b, c) __builtin_amdgcn_mfma_f32_16x16x32_fp8_fp8((a), (b), (c), 0, 0, 0)

// async 16B/lane global->LDS DMA; LDS dst = wave-uniform base + lane*16
#define ASYNC16(gsrc, ldst)                                                    \
    __builtin_amdgcn_global_load_lds(                                          \
        (__attribute__((address_space(1))) void*)(void*)(gsrc),                \
        (__attribute__((address_space(3))) void*)(ldst), 16, 0, 0)

static __device__ __forceinline__ unsigned short f2bf(float f) {
    union { float f; unsigned u; } v; v.f = f;
    unsigned r = v.u + 0x7fffu + ((v.u >> 16) & 1u);
    return (unsigned short)(r >> 16);
}
static __device__ __forceinline__ float bf2f(unsigned short h) {
    union { unsigned u; float f; } v; v.u = ((unsigned)h) << 16;
    return v.f;
}
static __device__ __forceinline__ unsigned char f2fp8(float f) {
    return (unsigned char)__builtin_amdgcn_cvt_pk_fp8_f32(f, f, 0, 0);
}

// ------- k_cc: [0,2144) convert; [2144,2152) compact+pad-zero; rest zero ----
__global__ __launch_bounds__(256) void k_cc(
    const float* __restrict__ nodes, const float* __restrict__ Wq,
    const float* __restrict__ Wk, const float* __restrict__ Wv,
    unsigned short* __restrict__ nbf, unsigned short* __restrict__ wbf,
    const int* __restrict__ mask, int* __restrict__ cnt,
    int* __restrict__ slot_of /* [16384] */,
    unsigned char* __restrict__ kbt,
    float* __restrict__ zbase /* lsum, 16384 f */,
    float* __restrict__ outp /* 2048 f */)
{
    int blk = blockIdx.x;
    if (blk < 2144) {                              // fp32 -> bf16 convert
        int unit = blk * 256 + threadIdx.x;        // one unit = 8 elements
        const float* src;
        unsigned short* dst;
        int off;
        if (unit < 524288) {
            src = nodes; dst = nbf; off = unit * 8;
        } else {
            int j = (unit - 524288) * 8;
            int m = j >> 16;
            int r = j & 65535;
            src = (m == 0) ? Wq : (m == 1 ? Wk : Wv);
            dst = wbf + m * 65536;
            off = r;
        }
        float4 a = *(const float4*)(src + off);
        float4 b = *(const float4*)(src + off + 4);
        short8 o;
        o[0] = f2bf(a.x); o[1] = f2bf(a.y); o[2] = f2bf(a.z); o[3] = f2bf(a.w);
        o[4] = f2bf(b.x); o[5] = f2bf(b.y); o[6] = f2bf(b.z); o[7] = f2bf(b.w);
        *(short8*)(dst + off) = o;
        return;
    }
    if (blk < 2152) {                              // key compaction + inverse map
        if (threadIdx.x < 64) {
            int b = blk - 2144, lane = threadIdx.x;
            int base = 0;
            for (int c = 0; c < 2048; c += 64) {
                int m = mask[b * 2048 + c + lane];
                unsigned long long bal = __ballot(m != 0);
                int pre = __popcll(bal & ((1ull << lane) - 1ull));
                slot_of[b * 2048 + c + lane] = m ? (base + pre) : -1;
                base += __popcll(bal);
            }
            if (lane == 0) cnt[b] = base;
            // zero kbt pad slots of the last chunk (fp8 0 -> exp killed by bias)
            int cntPad = (base + 63) & ~63;
            int pad = cntPad - base;               // [0, 64)
            for (int i = lane; i < pad * 32; i += 64) {
                int slot = base + (i >> 5);
                int du = i & 31;
                size_t off = ((size_t)b * 32 + (slot >> 6)) * 16384
                           + ((size_t)du * 64 + (slot & 63)) * 8;
                *(unsigned long long*)(kbt + off) = 0ull;
            }
        }
        return;
    }
    int idx = (blk - 2152) * 256 + threadIdx.x;    // [0, 4608)
    float4 z = {0.f, 0.f, 0.f, 0.f};
    if (idx < 4096) ((float4*)zbase)[idx] = z;     // lsum: 16384 floats
    else ((float4*)outp)[idx - 4096] = z;          // out: 2048 floats
}

// ------- k_proj2b: 128x128 LDS-tiled GEMM, async staging; K,V -> compacted --
// grid (128, 2, 3); block 256 = 4 waves (2x2), wave computes 64x64.
__global__ __launch_bounds__(256) void k_proj2b(
    const unsigned short* __restrict__ nbf,
    const unsigned short* __restrict__ wbf,
    const float* __restrict__ bq, const float* __restrict__ bk,
    const float* __restrict__ bv,
    const int* __restrict__ slot_of,
    unsigned char* __restrict__ qb, unsigned char* __restrict__ kbt,
    unsigned short* __restrict__ vbc)
{
    __shared__ __align__(16) unsigned short As[128 * 64];
    __shared__ __align__(16) unsigned short Bs[128 * 64];
    int tid = threadIdx.x, lane = tid & 63, wave = tid >> 6;
    int wm = wave & 1, wn = wave >> 1;
    int l15 = lane & 15, quad = lane >> 4;
    int mBase = blockIdx.x * 128;
    int nBase = blockIdx.y * 128;
    int z = blockIdx.z;
    const unsigned short* W = wbf + z * 65536;

    floatx4 acc[4][4] = {};

    for (int kc = 0; kc < 256; kc += 64) {
#pragma unroll
        for (int i = 0; i < 4; ++i) {
            int p = i * 256 + wave * 64 + lane;
            int row = p >> 3;
            int col8 = (p & 7) ^ (row & 7);
            int goff = row * 256 + kc + col8 * 8;
            unsigned short* dstA = &As[(i * 256 + wave * 64) * 8];
            unsigned short* dstB = &Bs[(i * 256 + wave * 64) * 8];
            ASYNC16(nbf + mBase * 256 + goff, dstA);
            ASYNC16(W + nBase * 256 + goff, dstB);
        }
        __syncthreads();
#pragma unroll
        for (int ks = 0; ks < 2; ++ks) {
            int c8 = ks * 4 + quad;
            short8 af[4], bfr[4];
#pragma unroll
            for (int i = 0; i < 4; ++i) {
                int row = wm * 64 + i * 16 + l15;
                af[i] = *(const short8*)(&As[(row * 8 + (c8 ^ (row & 7))) * 8]);
            }
#pragma unroll
            for (int i = 0; i < 4; ++i) {
                int row = wn * 64 + i * 16 + l15;
                bfr[i] = *(const short8*)(&Bs[(row * 8 + (c8 ^ (row & 7))) * 8]);
            }
#pragma unroll
            for (int mi = 0; mi < 4; ++mi)
#pragma unroll
                for (int ni = 0; ni < 4; ++ni)
                    acc[mi][ni] = MFMA16(af[mi], bfr[ni], acc[mi][ni]);
        }
        __syncthreads();
    }

    const float* bias = (z == 0) ? bq : (z == 1 ? bk : bv);
    if (z == 1) {
        // K path: fp8 x0.25, scatter into compacted fragment-tile layout
#pragma unroll
        for (int mi = 0; mi < 4; ++mi)
#pragma unroll
            for (int ni = 0; ni < 4; ++ni) {
                int col = nBase + wn * 64 + ni * 16 + l15;
                float bval = bias[col];
                int du = col >> 3, cj = col & 7;
#pragma unroll
                for (int r = 0; r < 4; ++r) {
                    int row = mBase + wm * 64 + mi * 16 + quad * 4 + r;
                    int slot = slot_of[row];
                    if (slot >= 0) {
                        int b = row >> 11;
                        size_t off = ((size_t)b * 32 + (slot >> 6)) * 16384
                                   + ((size_t)du * 64 + (slot & 63)) * 8 + cj;
                        kbt[off] = f2fp8((acc[mi][ni][r] + bval) * 0.25f);
                    }
                }
            }
    } else if (z == 2) {
        // V path: scatter into slot-compacted [b][slot][d] bf16 layout
#pragma unroll
        for (int mi = 0; mi < 4; ++mi)
#pragma unroll
            for (int ni = 0; ni < 4; ++ni) {
                int col = nBase + wn * 64 + ni * 16 + l15;
                float bval = bias[col];
#pragma unroll
                for (int r = 0; r < 4; ++r) {
                    int row = mBase + wm * 64 + mi * 16 + quad * 4 + r;
                    int slot = slot_of[row];
                    if (slot >= 0) {
                        int b = row >> 11;
                        vbc[((size_t)b * 2048 + slot) * 256 + col] =
                            f2bf(acc[mi][ni][r] + bval);
                    }
                }
            }
    } else {
        // Q path: fp8 x(0.25*log2e) -> with K's 0.25, acc = s*log2e for exp2
        const float scale = 0.25f * 1.44269504088896f;
#pragma unroll
        for (int mi = 0; mi < 4; ++mi)
#pragma unroll
            for (int ni = 0; ni < 4; ++ni) {
                int col = nBase + wn * 64 + ni * 16 + l15;
                float bval = bias[col];
#pragma unroll
                for (int r = 0; r < 4; ++r) {
                    int row = mBase + wm * 64 + mi * 16 + quad * 4 + r;
                    qb[row * 256 + col] = f2fp8((acc[mi][ni][r] + bval) * scale);
                }
            }
    }
}

// ---------------- k_pass1v: QK^T fp8, dbuf async staging, fp8 P -------------
// grid (8 qblk, 4 ksplit, 8 b); block 512 = 8 waves; wave owns 32 queries.
// Chunk = 16KB fp8. Counted vmcnt(2) before raw s_barrier keeps next chunk's
// DMA in flight; vmcnt(0) only on the final chunk. P = exp2(acc) via raw
// v_exp_f32 (log2e folded into Q's fp8 scale).
// P tile: [b][ktile(<96)][qcg(64)][lane(64)][8 fp8] (8B coalesced stores).
__global__ __launch_bounds__(512, 2) void k_pass1v(
    const unsigned char* __restrict__ qb, const unsigned char* __restrict__ kbt,
    const int* __restrict__ cnt_g, float* __restrict__ lsum_g,
    unsigned char* __restrict__ pbuf)
{
    __shared__ __align__(16) unsigned char kt[2][16384];   // 2x16KB dbuf
    int tid = threadIdx.x, lane = tid & 63, wave = tid >> 6;
    int l15 = lane & 15, quad = lane >> 4;
    int b = blockIdx.z;
    int cnt = cnt_g[b];
    int nchunk = (cnt + 63) >> 6;
    int qBase = blockIdx.x * 256 + wave * 32;
    int qcg = blockIdx.x * 8 + wave;

    long qf[2][8];
#pragma unroll
    for (int mi = 0; mi < 2; ++mi)
#pragma unroll
        for (int ks = 0; ks < 8; ++ks)
            qf[mi][ks] = *(const long*)(qb + (size_t)(b * 2048 + qBase + mi * 16 + l15) * 256 + ks * 32 + quad * 8);

    // prologue: stage first chunk into buf 0 (8 waves x 2 segs = 16 x 1KB)
    {
        const unsigned char* src = kbt + ((size_t)b * 32 + blockIdx.y) * 16384;
#pragma unroll
        for (int i = 0; i < 2; ++i) {
            int seg = wave * 2 + i;
            ASYNC16(src + seg * 1024 + lane * 16, &kt[0][seg * 1024]);
        }
    }

    float ls[2][4] = {};
    int p = 0;
    for (int c = blockIdx.y; c < nchunk; c += 4, p ^= 1) {
        int cn = c + 4;
        if (cn < nchunk) {                 // prefetch next chunk into other buf
            const unsigned char* srcn = kbt + ((size_t)b * 32 + cn) * 16384;
#pragma unroll
            for (int i = 0; i < 2; ++i) {
                int seg = wave * 2 + i;
                ASYNC16(srcn + seg * 1024 + lane * 16, &kt[p ^ 1][seg * 1024]);
            }
            asm volatile("s_waitcnt vmcnt(2)" ::: "memory");  // cur chunk done
        } else {
            asm volatile("s_waitcnt vmcnt(0)" ::: "memory");
        }
        __builtin_amdgcn_s_barrier();
#pragma unroll
        for (int nt = 0; nt < 4; ++nt) {
            long kf[8];
#pragma unroll
            for (int ks = 0; ks < 8; ++ks)
                kf[ks] = *(const long*)(&kt[p][((ks * 4 + quad) * 64 + nt * 16 + l15) * 8]);
            floatx4 acc[2] = {};
#pragma unroll
            for (int ks = 0; ks < 8; ++ks) {
                acc[0] = MFMA8(qf[0][ks], kf[ks], acc[0]);
                acc[1] = MFMA8(qf[1][ks], kf[ks], acc[1]);
            }
            float bias = (c * 64 + nt * 16 + l15 < cnt) ? 0.0f : -1e30f;
            float e[2][4];
#pragma unroll
            for (int mi = 0; mi < 2; ++mi)
#pragma unroll
                for (int r = 0; r < 4; ++r) {
                    e[mi][r] = __builtin_amdgcn_exp2f(acc[mi][r] + bias);
                    ls[mi][r] += e[mi][r];
                }
            int ktile = c * 4 + nt;
            if (ktile < 96) {
                int w0 = __builtin_amdgcn_cvt_pk_fp8_f32(e[0][0], e[0][1], 0, 0);
                w0 = __builtin_amdgcn_cvt_pk_fp8_f32(e[0][2], e[0][3], w0, 1);
                int w1 = __builtin_amdgcn_cvt_pk_fp8_f32(e[1][0], e[1][1], 0, 0);
                w1 = __builtin_amdgcn_cvt_pk_fp8_f32(e[1][2], e[1][3], w1, 1);
                size_t off = ((((size_t)b * 96 + ktile) * 64 + qcg) * 64 + lane) * 8;
                uint2 pv; pv.x = (unsigned)w0; pv.y = (unsigned)w1;
                *(uint2*)(pbuf + off) = pv;
            }
        }
        __builtin_amdgcn_s_barrier();      // all reads of kt[p] done before
    }                                      // it gets re-staged next+1 iter
#pragma unroll
    for (int mi = 0; mi < 2; ++mi)
#pragma unroll
        for (int r = 0; r < 4; ++r) {
            float v = ls[mi][r];
            v += __shfl_xor(v, 1); v += __shfl_xor(v, 2);
            v += __shfl_xor(v, 4); v += __shfl_xor(v, 8);
            if (l15 == 0)
                atomicAdd(&lsum_g[b * 2048 + qBase + mi * 16 + quad * 4 + r], v);
        }
}

// ---- k_wo: fused w-reduce + out. grid (48 kblk, 8 b); block 256 = 4 waves.
// wave (qh, kt2): reduce 32 qcg for ktile = bx*2+kt2 -> w in LDS; then each
// thread owns one d: out[b,d] += sum over the block's 32 slots of w * vbc.
__global__ __launch_bounds__(256) void k_wo(
    const unsigned char* __restrict__ pbuf, const float* __restrict__ lsum_g,
    const int* __restrict__ cnt_g, const unsigned short* __restrict__ vbc,
    float* __restrict__ outp)
{
    __shared__ float linv_p[2048];   // [qcg(64)][quad(4)][mi*4+r(8)]
    __shared__ float w2_s[2][32];
    int tid = threadIdx.x, lane = tid & 63, wave = tid >> 6;
    int l15 = lane & 15, quad = lane >> 4;
    int b = blockIdx.y;
    int kt2 = wave & 1;
    int qh = wave >> 1;
    int ktile = blockIdx.x * 2 + kt2;              // [0, 96)

#pragma unroll
    for (int i = 0; i < 8; ++i) {
        int idx = i * 256 + tid;
        int qcg = idx >> 5, qd = (idx >> 3) & 3, j = idx & 7;
        int q = qcg * 32 + (j >> 2) * 16 + qd * 4 + (j & 3);
        linv_p[idx] = 1.0f / lsum_g[b * 2048 + q];
    }
    __syncthreads();

    int cnt = cnt_g[b];
    float acc = 0.f;
    if (ktile * 16 < cnt) {
        int qcg0 = qh * 32;
#pragma unroll 4
        for (int qcg = qcg0; qcg < qcg0 + 32; ++qcg) {
            size_t off = ((((size_t)b * 96 + ktile) * 64 + qcg) * 64 + lane) * 8;
            uint2 pv = *(const uint2*)(pbuf + off);
            const float* lv = &linv_p[(qcg * 4 + quad) * 8];
            floatx2 p01 = __builtin_amdgcn_cvt_pk_f32_fp8(pv.x, 0);
            floatx2 p23 = __builtin_amdgcn_cvt_pk_f32_fp8(pv.x, 1);
            floatx2 p45 = __builtin_amdgcn_cvt_pk_f32_fp8(pv.y, 0);
            floatx2 p67 = __builtin_amdgcn_cvt_pk_f32_fp8(pv.y, 1);
            acc += p01[0] * lv[0] + p01[1] * lv[1] + p23[0] * lv[2] + p23[1] * lv[3]
                 + p45[0] * lv[4] + p45[1] * lv[5] + p67[0] * lv[6] + p67[1] * lv[7];
        }
    }
    acc += __shfl_xor(acc, 16);
    acc += __shfl_xor(acc, 32);
    int slot = ktile * 16 + l15;
    if (lane < 16)
        w2_s[qh][kt2 * 16 + l15] = (slot < cnt) ? acc : 0.f;
    __syncthreads();

    // out phase: one thread per d, sum the block's 32 slots
    int d = tid;
    float oacc = 0.f;
#pragma unroll 4
    for (int sl = 0; sl < 32; ++sl) {
        float w = w2_s[0][sl] + w2_s[1][sl];
        if (w != 0.f) {                            // also guards unwritten vbc
            int sg = blockIdx.x * 32 + sl;
            oacc += w * bf2f(vbc[((size_t)b * 2048 + sg) * 256 + d]);
        }
    }
    atomicAdd(&outp[b * 256 + d], oacc * (1.0f / 2048.0f));
}

extern "C" void kernel_launch(void* const* d_in, const int* in_sizes, int n_in,
                              void* d_out, int out_size, void* d_ws, size_t ws_size,
                              hipStream_t stream)
{
    const float* nodes = (const float*)d_in[0];
    const int*   mask  = (const int*)d_in[1];
    const float* Wq    = (const float*)d_in[2];
    const float* bq    = (const float*)d_in[3];
    const float* Wk    = (const float*)d_in[4];
    const float* bk    = (const float*)d_in[5];
    const float* Wv    = (const float*)d_in[6];
    const float* bv    = (const float*)d_in[7];
    float* out = (float*)d_out;

    // workspace layout (same 8MB slot spacing as R7; qb/kbt fp8, use half)
    unsigned char*  qb  = (unsigned char*)d_ws;                 // 4 MB of 8 MB slot
    unsigned short* vbc = (unsigned short*)d_ws + 4194304;      // 8 MB (bf16 V)
    float* lsum = (float*)(vbc + 4194304);                      // 64 KB
    int*   cnt  = (int*)(lsum + 16384);                         // 64 B
    int*   slot_of = cnt + 16;                                  // 64 KB
    unsigned char* kbt = (unsigned char*)(slot_of + 16384);     // 4 MB of 8 MB slot
    unsigned short* X  = (unsigned short*)(kbt + 8388608);
    unsigned short* nbf = X;                                    // 8 MB  (convert/proj)
    unsigned short* wbf = X + 4194304;                          // 0.4 MB (convert/proj)
    unsigned char* pbuf = (unsigned char*)X;                    // 25.2 MB (pass1 onward)

    k_cc<<<2170, 256, 0, stream>>>(nodes, Wq, Wk, Wv, nbf, wbf,
                                   mask, cnt, slot_of, kbt, lsum, out);
    k_proj2b<<<dim3(128, 2, 3), 256, 0, stream>>>(nbf, wbf, bq, bk, bv,
                                                  slot_of, qb, kbt, vbc);
    k_pass1v<<<dim3(8, 4, 8), 512, 0, stream>>>(qb, kbt, cnt, lsum, pbuf);
    k_wo<<<dim3(48, 8), 256, 0, stream>>>(pbuf, lsum, cnt, vbc, out);
}

// Round 12
// 129.298 us; speedup vs baseline: 1.0326x; 1.0142x over previous
//
#include <hip/hip_runtime.h>
#include <hip/hip_bf16.h>
#include <stdint.h>

// B=8, S=2048, D=256. out[b,d] = (1/S) sum_k w_k v[b,k,d],
// w_k = sum_q P_qk / l_q,  P_qk = exp(s_qk) (0 for masked k), l_q = sum_k P_qk.
//
// FINAL (banking round): R9 configuration verbatim = 130.2us, the best of 12
// measured variants. Ledger: dur_us ~= sum(ours ~43us) + ~87us fixed harness
// fill (2x 256MB workspace poison at ~78-80% achievable HBM BW).
// Confirmed wins: wred+out fusion (-8.2), 256-q pass1 tile (-2.2), fp8 QK
// (-1.2). Confirmed nulls/regressions: traffic deletion, XCD affinity,
// register-direct K, flash PV fusion, ksplit 8 (x2), reg-staged A, exp2 fold.
//
// k_cc:     fp32->bf16 convert + key compaction (slot_of inverse map +
//           kbt pad-chunk zeroing) + lsum/out zeroing.
// k_proj2b: QKV projection GEMM, LDS-tiled, async-DMA staging; z=0 -> qb fp8
//           (x0.25), z=1 -> kbt fp8 fragment tiles (x0.25), z=2 -> vbc bf16.
// k_pass1v: QK^T fp8 via dbuf global_load_lds staging -> l_q + P tiles (fp8).
// k_wo:     fused: w_k = sum_q P[q][k]/l_q (fp8 P) then out += w . V, w in LDS.

typedef short short8 __attribute__((ext_vector_type(8)));
typedef float floatx4 __attribute__((ext_vector_type(4)));
typedef float floatx2 __attribute__((ext_vector_type(2)));

#define MFMA16(a, b, c) __builtin_amdgcn_mfma_f32_16x16x32_bf16((a), (b), (c), 0, 0, 0)
#define MFMA8(a, b, c) __builtin_amdgcn_mfma_f32_16x16x32_fp8_fp8((a), (b), (c), 0, 0, 0)

// async 16B/lane global->LDS DMA; LDS dst = wave-uniform base + lane*16
#define ASYNC16(gsrc, ldst)                                                    \
    __builtin_amdgcn_global_load_lds(                                          \
        (__attribute__((address_space(1))) void*)(void*)(gsrc),                \
        (__attribute__((address_space(3))) void*)(ldst), 16, 0, 0)

static __device__ __forceinline__ unsigned short f2bf(float f) {
    union { float f; unsigned u; } v; v.f = f;
    unsigned r = v.u + 0x7fffu + ((v.u >> 16) & 1u);
    return (unsigned short)(r >> 16);
}
static __device__ __forceinline__ float bf2f(unsigned short h) {
    union { unsigned u; float f; } v; v.u = ((unsigned)h) << 16;
    return v.f;
}
static __device__ __forceinline__ unsigned char f2fp8(float f) {
    return (unsigned char)__builtin_amdgcn_cvt_pk_fp8_f32(f, f, 0, 0);
}

// ------- k_cc: [0,2144) convert; [2144,2152) compact+pad-zero; rest zero ----
__global__ __launch_bounds__(256) void k_cc(
    const float* __restrict__ nodes, const float* __restrict__ Wq,
    const float* __restrict__ Wk, const float* __restrict__ Wv,
    unsigned short* __restrict__ nbf, unsigned short* __restrict__ wbf,
    const int* __restrict__ mask, int* __restrict__ cnt,
    int* __restrict__ slot_of /* [16384] */,
    unsigned char* __restrict__ kbt,
    float* __restrict__ zbase /* lsum, 16384 f */,
    float* __restrict__ outp /* 2048 f */)
{
    int blk = blockIdx.x;
    if (blk < 2144) {                              // fp32 -> bf16 convert
        int unit = blk * 256 + threadIdx.x;        // one unit = 8 elements
        const float* src;
        unsigned short* dst;
        int off;
        if (unit < 524288) {
            src = nodes; dst = nbf; off = unit * 8;
        } else {
            int j = (unit - 524288) * 8;
            int m = j >> 16;
            int r = j & 65535;
            src = (m == 0) ? Wq : (m == 1 ? Wk : Wv);
            dst = wbf + m * 65536;
            off = r;
        }
        float4 a = *(const float4*)(src + off);
        float4 b = *(const float4*)(src + off + 4);
        short8 o;
        o[0] = f2bf(a.x); o[1] = f2bf(a.y); o[2] = f2bf(a.z); o[3] = f2bf(a.w);
        o[4] = f2bf(b.x); o[5] = f2bf(b.y); o[6] = f2bf(b.z); o[7] = f2bf(b.w);
        *(short8*)(dst + off) = o;
        return;
    }
    if (blk < 2152) {                              // key compaction + inverse map
        if (threadIdx.x < 64) {
            int b = blk - 2144, lane = threadIdx.x;
            int base = 0;
            for (int c = 0; c < 2048; c += 64) {
                int m = mask[b * 2048 + c + lane];
                unsigned long long bal = __ballot(m != 0);
                int pre = __popcll(bal & ((1ull << lane) - 1ull));
                slot_of[b * 2048 + c + lane] = m ? (base + pre) : -1;
                base += __popcll(bal);
            }
            if (lane == 0) cnt[b] = base;
            // zero kbt pad slots of the last chunk (fp8 0 -> exp killed by bias)
            int cntPad = (base + 63) & ~63;
            int pad = cntPad - base;               // [0, 64)
            for (int i = lane; i < pad * 32; i += 64) {
                int slot = base + (i >> 5);
                int du = i & 31;
                size_t off = ((size_t)b * 32 + (slot >> 6)) * 16384
                           + ((size_t)du * 64 + (slot & 63)) * 8;
                *(unsigned long long*)(kbt + off) = 0ull;
            }
        }
        return;
    }
    int idx = (blk - 2152) * 256 + threadIdx.x;    // [0, 4608)
    float4 z = {0.f, 0.f, 0.f, 0.f};
    if (idx < 4096) ((float4*)zbase)[idx] = z;     // lsum: 16384 floats
    else ((float4*)outp)[idx - 4096] = z;          // out: 2048 floats
}

// ------- k_proj2b: 128x128 LDS-tiled GEMM, async staging; K,V -> compacted --
// grid (128, 2, 3); block 256 = 4 waves (2x2), wave computes 64x64.
__global__ __launch_bounds__(256) void k_proj2b(
    const unsigned short* __restrict__ nbf,
    const unsigned short* __restrict__ wbf,
    const float* __restrict__ bq, const float* __restrict__ bk,
    const float* __restrict__ bv,
    const int* __restrict__ slot_of,
    unsigned char* __restrict__ qb, unsigned char* __restrict__ kbt,
    unsigned short* __restrict__ vbc)
{
    __shared__ __align__(16) unsigned short As[128 * 64];
    __shared__ __align__(16) unsigned short Bs[128 * 64];
    int tid = threadIdx.x, lane = tid & 63, wave = tid >> 6;
    int wm = wave & 1, wn = wave >> 1;
    int l15 = lane & 15, quad = lane >> 4;
    int mBase = blockIdx.x * 128;
    int nBase = blockIdx.y * 128;
    int z = blockIdx.z;
    const unsigned short* W = wbf + z * 65536;

    floatx4 acc[4][4] = {};

    for (int kc = 0; kc < 256; kc += 64) {
#pragma unroll
        for (int i = 0; i < 4; ++i) {
            int p = i * 256 + wave * 64 + lane;
            int row = p >> 3;
            int col8 = (p & 7) ^ (row & 7);
            int goff = row * 256 + kc + col8 * 8;
            unsigned short* dstA = &As[(i * 256 + wave * 64) * 8];
            unsigned short* dstB = &Bs[(i * 256 + wave * 64) * 8];
            ASYNC16(nbf + mBase * 256 + goff, dstA);
            ASYNC16(W + nBase * 256 + goff, dstB);
        }
        __syncthreads();
#pragma unroll
        for (int ks = 0; ks < 2; ++ks) {
            int c8 = ks * 4 + quad;
            short8 af[4], bfr[4];
#pragma unroll
            for (int i = 0; i < 4; ++i) {
                int row = wm * 64 + i * 16 + l15;
                af[i] = *(const short8*)(&As[(row * 8 + (c8 ^ (row & 7))) * 8]);
            }
#pragma unroll
            for (int i = 0; i < 4; ++i) {
                int row = wn * 64 + i * 16 + l15;
                bfr[i] = *(const short8*)(&Bs[(row * 8 + (c8 ^ (row & 7))) * 8]);
            }
#pragma unroll
            for (int mi = 0; mi < 4; ++mi)
#pragma unroll
                for (int ni = 0; ni < 4; ++ni)
                    acc[mi][ni] = MFMA16(af[mi], bfr[ni], acc[mi][ni]);
        }
        __syncthreads();
    }

    const float* bias = (z == 0) ? bq : (z == 1 ? bk : bv);
    if (z == 1) {
        // K path: fp8 x0.25, scatter into compacted fragment-tile layout
#pragma unroll
        for (int mi = 0; mi < 4; ++mi)
#pragma unroll
            for (int ni = 0; ni < 4; ++ni) {
                int col = nBase + wn * 64 + ni * 16 + l15;
                float bval = bias[col];
                int du = col >> 3, cj = col & 7;
#pragma unroll
                for (int r = 0; r < 4; ++r) {
                    int row = mBase + wm * 64 + mi * 16 + quad * 4 + r;
                    int slot = slot_of[row];
                    if (slot >= 0) {
                        int b = row >> 11;
                        size_t off = ((size_t)b * 32 + (slot >> 6)) * 16384
                                   + ((size_t)du * 64 + (slot & 63)) * 8 + cj;
                        kbt[off] = f2fp8((acc[mi][ni][r] + bval) * 0.25f);
                    }
                }
            }
    } else if (z == 2) {
        // V path: scatter into slot-compacted [b][slot][d] bf16 layout
#pragma unroll
        for (int mi = 0; mi < 4; ++mi)
#pragma unroll
            for (int ni = 0; ni < 4; ++ni) {
                int col = nBase + wn * 64 + ni * 16 + l15;
                float bval = bias[col];
#pragma unroll
                for (int r = 0; r < 4; ++r) {
                    int row = mBase + wm * 64 + mi * 16 + quad * 4 + r;
                    int slot = slot_of[row];
                    if (slot >= 0) {
                        int b = row >> 11;
                        vbc[((size_t)b * 2048 + slot) * 256 + col] =
                            f2bf(acc[mi][ni][r] + bval);
                    }
                }
            }
    } else {
        // Q path: fp8 x0.25 (with K's 0.25 -> total 1/16 = 1/sqrt(256))
#pragma unroll
        for (int mi = 0; mi < 4; ++mi)
#pragma unroll
            for (int ni = 0; ni < 4; ++ni) {
                int col = nBase + wn * 64 + ni * 16 + l15;
                float bval = bias[col];
#pragma unroll
                for (int r = 0; r < 4; ++r) {
                    int row = mBase + wm * 64 + mi * 16 + quad * 4 + r;
                    qb[row * 256 + col] = f2fp8((acc[mi][ni][r] + bval) * 0.25f);
                }
            }
    }
}

// ---------------- k_pass1v: QK^T fp8, dbuf async staging, fp8 P -------------
// grid (8 qblk, 4 ksplit, 8 b); block 512 = 8 waves; wave owns 32 queries.
// Chunk = 16KB fp8 (was 32KB bf16): staging and LDS reads halve. Counted
// vmcnt(2) before raw s_barrier keeps next chunk's DMA in flight; vmcnt(0)
// only on the final chunk.
// P tile: [b][ktile(<96)][qcg(64)][lane(64)][8 fp8] (8B coalesced stores).
__global__ __launch_bounds__(512, 2) void k_pass1v(
    const unsigned char* __restrict__ qb, const unsigned char* __restrict__ kbt,
    const int* __restrict__ cnt_g, float* __restrict__ lsum_g,
    unsigned char* __restrict__ pbuf)
{
    __shared__ __align__(16) unsigned char kt[2][16384];   // 2x16KB dbuf
    int tid = threadIdx.x, lane = tid & 63, wave = tid >> 6;
    int l15 = lane & 15, quad = lane >> 4;
    int b = blockIdx.z;
    int cnt = cnt_g[b];
    int nchunk = (cnt + 63) >> 6;
    int qBase = blockIdx.x * 256 + wave * 32;
    int qcg = blockIdx.x * 8 + wave;

    long qf[2][8];
#pragma unroll
    for (int mi = 0; mi < 2; ++mi)
#pragma unroll
        for (int ks = 0; ks < 8; ++ks)
            qf[mi][ks] = *(const long*)(qb + (size_t)(b * 2048 + qBase + mi * 16 + l15) * 256 + ks * 32 + quad * 8);

    // prologue: stage first chunk into buf 0 (8 waves x 2 segs = 16 x 1KB)
    {
        const unsigned char* src = kbt + ((size_t)b * 32 + blockIdx.y) * 16384;
#pragma unroll
        for (int i = 0; i < 2; ++i) {
            int seg = wave * 2 + i;
            ASYNC16(src + seg * 1024 + lane * 16, &kt[0][seg * 1024]);
        }
    }

    float ls[2][4] = {};
    int p = 0;
    for (int c = blockIdx.y; c < nchunk; c += 4, p ^= 1) {
        int cn = c + 4;
        if (cn < nchunk) {                 // prefetch next chunk into other buf
            const unsigned char* srcn = kbt + ((size_t)b * 32 + cn) * 16384;
#pragma unroll
            for (int i = 0; i < 2; ++i) {
                int seg = wave * 2 + i;
                ASYNC16(srcn + seg * 1024 + lane * 16, &kt[p ^ 1][seg * 1024]);
            }
            asm volatile("s_waitcnt vmcnt(2)" ::: "memory");  // cur chunk done
        } else {
            asm volatile("s_waitcnt vmcnt(0)" ::: "memory");
        }
        __builtin_amdgcn_s_barrier();
#pragma unroll
        for (int nt = 0; nt < 4; ++nt) {
            long kf[8];
#pragma unroll
            for (int ks = 0; ks < 8; ++ks)
                kf[ks] = *(const long*)(&kt[p][((ks * 4 + quad) * 64 + nt * 16 + l15) * 8]);
            floatx4 acc[2] = {};
#pragma unroll
            for (int ks = 0; ks < 8; ++ks) {
                acc[0] = MFMA8(qf[0][ks], kf[ks], acc[0]);
                acc[1] = MFMA8(qf[1][ks], kf[ks], acc[1]);
            }
            float bias = (c * 64 + nt * 16 + l15 < cnt) ? 0.0f : -1e30f;
            float e[2][4];
#pragma unroll
            for (int mi = 0; mi < 2; ++mi)
#pragma unroll
                for (int r = 0; r < 4; ++r) {
                    e[mi][r] = __expf(acc[mi][r] + bias);
                    ls[mi][r] += e[mi][r];
                }
            int ktile = c * 4 + nt;
            if (ktile < 96) {
                int w0 = __builtin_amdgcn_cvt_pk_fp8_f32(e[0][0], e[0][1], 0, 0);
                w0 = __builtin_amdgcn_cvt_pk_fp8_f32(e[0][2], e[0][3], w0, 1);
                int w1 = __builtin_amdgcn_cvt_pk_fp8_f32(e[1][0], e[1][1], 0, 0);
                w1 = __builtin_amdgcn_cvt_pk_fp8_f32(e[1][2], e[1][3], w1, 1);
                size_t off = ((((size_t)b * 96 + ktile) * 64 + qcg) * 64 + lane) * 8;
                uint2 pv; pv.x = (unsigned)w0; pv.y = (unsigned)w1;
                *(uint2*)(pbuf + off) = pv;
            }
        }
        __builtin_amdgcn_s_barrier();      // all reads of kt[p] done before
    }                                      // it gets re-staged next+1 iter
#pragma unroll
    for (int mi = 0; mi < 2; ++mi)
#pragma unroll
        for (int r = 0; r < 4; ++r) {
            float v = ls[mi][r];
            v += __shfl_xor(v, 1); v += __shfl_xor(v, 2);
            v += __shfl_xor(v, 4); v += __shfl_xor(v, 8);
            if (l15 == 0)
                atomicAdd(&lsum_g[b * 2048 + qBase + mi * 16 + quad * 4 + r], v);
        }
}

// ---- k_wo: fused w-reduce + out. grid (48 kblk, 8 b); block 256 = 4 waves.
// wave (qh, kt2): reduce 32 qcg for ktile = bx*2+kt2 -> w in LDS; then each
// thread owns one d: out[b,d] += sum over the block's 32 slots of w * vbc.
__global__ __launch_bounds__(256) void k_wo(
    const unsigned char* __restrict__ pbuf, const float* __restrict__ lsum_g,
    const int* __restrict__ cnt_g, const unsigned short* __restrict__ vbc,
    float* __restrict__ outp)
{
    __shared__ float linv_p[2048];   // [qcg(64)][quad(4)][mi*4+r(8)]
    __shared__ float w2_s[2][32];
    int tid = threadIdx.x, lane = tid & 63, wave = tid >> 6;
    int l15 = lane & 15, quad = lane >> 4;
    int b = blockIdx.y;
    int kt2 = wave & 1;
    int qh = wave >> 1;
    int ktile = blockIdx.x * 2 + kt2;              // [0, 96)

#pragma unroll
    for (int i = 0; i < 8; ++i) {
        int idx = i * 256 + tid;
        int qcg = idx >> 5, qd = (idx >> 3) & 3, j = idx & 7;
        int q = qcg * 32 + (j >> 2) * 16 + qd * 4 + (j & 3);
        linv_p[idx] = 1.0f / lsum_g[b * 2048 + q];
    }
    __syncthreads();

    int cnt = cnt_g[b];
    float acc = 0.f;
    if (ktile * 16 < cnt) {
        int qcg0 = qh * 32;
#pragma unroll 4
        for (int qcg = qcg0; qcg < qcg0 + 32; ++qcg) {
            size_t off = ((((size_t)b * 96 + ktile) * 64 + qcg) * 64 + lane) * 8;
            uint2 pv = *(const uint2*)(pbuf + off);
            const float* lv = &linv_p[(qcg * 4 + quad) * 8];
            floatx2 p01 = __builtin_amdgcn_cvt_pk_f32_fp8(pv.x, 0);
            floatx2 p23 = __builtin_amdgcn_cvt_pk_f32_fp8(pv.x, 1);
            floatx2 p45 = __builtin_amdgcn_cvt_pk_f32_fp8(pv.y, 0);
            floatx2 p67 = __builtin_amdgcn_cvt_pk_f32_fp8(pv.y, 1);
            acc += p01[0] * lv[0] + p01[1] * lv[1] + p23[0] * lv[2] + p23[1] * lv[3]
                 + p45[0] * lv[4] + p45[1] * lv[5] + p67[0] * lv[6] + p67[1] * lv[7];
        }
    }
    acc += __shfl_xor(acc, 16);
    acc += __shfl_xor(acc, 32);
    int slot = ktile * 16 + l15;
    if (lane < 16)
        w2_s[qh][kt2 * 16 + l15] = (slot < cnt) ? acc : 0.f;
    __syncthreads();

    // out phase: one thread per d, sum the block's 32 slots
    int d = tid;
    float oacc = 0.f;
#pragma unroll 4
    for (int sl = 0; sl < 32; ++sl) {
        float w = w2_s[0][sl] + w2_s[1][sl];
        if (w != 0.f) {                            // also guards unwritten vbc
            int sg = blockIdx.x * 32 + sl;
            oacc += w * bf2f(vbc[((size_t)b * 2048 + sg) * 256 + d]);
        }
    }
    atomicAdd(&outp[b * 256 + d], oacc * (1.0f / 2048.0f));
}

extern "C" void kernel_launch(void* const* d_in, const int* in_sizes, int n_in,
                              void* d_out, int out_size, void* d_ws, size_t ws_size,
                              hipStream_t stream)
{
    const float* nodes = (const float*)d_in[0];
    const int*   mask  = (const int*)d_in[1];
    const float* Wq    = (const float*)d_in[2];
    const float* bq    = (const float*)d_in[3];
    const float* Wk    = (const float*)d_in[4];
    const float* bk    = (const float*)d_in[5];
    const float* Wv    = (const float*)d_in[6];
    const float* bv    = (const float*)d_in[7];
    float* out = (float*)d_out;

    // workspace layout (same 8MB slot spacing as R7; qb/kbt fp8, use half)
    unsigned char*  qb  = (unsigned char*)d_ws;                 // 4 MB of 8 MB slot
    unsigned short* vbc = (unsigned short*)d_ws + 4194304;      // 8 MB (bf16 V)
    float* lsum = (float*)(vbc + 4194304);                      // 64 KB
    int*   cnt  = (int*)(lsum + 16384);                         // 64 B
    int*   slot_of = cnt + 16;                                  // 64 KB
    unsigned char* kbt = (unsigned char*)(slot_of + 16384);     // 4 MB of 8 MB slot
    unsigned short* X  = (unsigned short*)(kbt + 8388608);
    unsigned short* nbf = X;                                    // 8 MB  (convert/proj)
    unsigned short* wbf = X + 4194304;                          // 0.4 MB (convert/proj)
    unsigned char* pbuf = (unsigned char*)X;                    // 25.2 MB (pass1 onward)

    k_cc<<<2170, 256, 0, stream>>>(nodes, Wq, Wk, Wv, nbf, wbf,
                                   mask, cnt, slot_of, kbt, lsum, out);
    k_proj2b<<<dim3(128, 2, 3), 256, 0, stream>>>(nbf, wbf, bq, bk, bv,
                                                  slot_of, qb, kbt, vbc);
    k_pass1v<<<dim3(8, 4, 8), 512, 0, stream>>>(qb, kbt, cnt, lsum, pbuf);
    k_wo<<<dim3(48, 8), 256, 0, stream>>>(pbuf, lsum, cnt, vbc, out);
}